// Round 1
// 698.995 us; speedup vs baseline: 1.1100x; 1.1100x over previous
//
#include <hip/hip_runtime.h>

// RelPosEmbedder: out[p,c] = tok[p,:42] @ W[66:108,c] + W[d_res,c] + ent*W[108,c] + W[109+d_chain,c]
// ent + chain terms are FOLDED into the MFMA via spare K columns (42..48):
// A cols 0..41 = tok, col 42 = ent, cols 43..48 = one_hot(d_chain), 49..63 = 0
// B rows k<49 = W[66+k]  (W rows 66..114 are contiguous: tok, ent, chain)
// Epilogue adds only W[d_res] (fp32, LDS, padded stride).
// Double-buffered A tile: prefetch next chunk into regs before compute, 1 barrier/chunk.

typedef __attribute__((ext_vector_type(8))) short short8;
typedef __attribute__((ext_vector_type(4))) float floatx4;

#define NSEQ    1024
#define CZ      128
#define CHUNK   64          // pairs per chunk
#define NCHUNK  8           // chunks per block -> 512 pairs/block
#define THREADS 256
#define KW      49          // folded K width: 42 tok + 1 ent + 6 chain
#define TOKF2   21          // float2 elements per pair row (42 f32)
#define LDS_AW  36          // dwords per A row: 32 data (64 bf16) + 4 bank-pad
#define WPAD    132         // lds_W row stride in floats (128 + 4: breaks 4-way conflict)
#define NWROWS  66          // gather rows 0..65 (d_res)

__device__ __forceinline__ unsigned short f2bf(float f) {
    union { float f; unsigned int i; } v; v.f = f;
    unsigned int i = v.i;
    return (unsigned short)((i + 0x7fffu + ((i >> 16) & 1u)) >> 16);   // RNE
}
__device__ __forceinline__ unsigned int packbf2(float x, float y) {
    return ((unsigned int)f2bf(y) << 16) | (unsigned int)f2bf(x);
}

__global__ __launch_bounds__(THREADS, 3) void relpos_kernel(
    const float* __restrict__ tok,   // [N*N, 42] f32
    const float* __restrict__ W,     // [115, 128] f32
    const int* __restrict__ asym,
    const int* __restrict__ sym,
    const int* __restrict__ eid,
    const int* __restrict__ res,
    float* __restrict__ out)         // [N*N, 128] f32
{
    __shared__ __align__(16) unsigned int lds_Au[2 * CHUNK * LDS_AW];  // double-buffered A, packed bf16
    __shared__ __align__(16) float lds_W[NWROWS * WPAD];               // d_res gather rows, fp32
    __shared__ int lds_flags[2 * CHUNK];                               // d_res per pair, double-buffered

    const int tid  = threadIdx.x;
    const int lane = tid & 63;
    const int wv   = tid >> 6;
    const int n    = lane & 15;   // MFMA col within 16-tile / A row m
    const int q    = lane >> 4;   // quad

    // ---- one-time: stage gather rows 0..65 (fp32, padded stride) ----
    for (int u4 = tid; u4 < NWROWS * (CZ / 4); u4 += THREADS) {
        int row = u4 >> 5, c4 = (u4 & 31) << 2;
        *(float4*)&lds_W[row * WPAD + c4] = *(const float4*)&W[row * CZ + c4];
    }
    // ---- one-time: zero both A buffers (K-pad cols 49..63 stay zero forever) ----
    for (int u = tid; u < 2 * CHUNK * LDS_AW; u += THREADS) lds_Au[u] = 0u;

    // ---- one-time: B fragments (W rows 66..114 as bf16, K zero-padded to 64) ----
    short8 bfrag[2][8];
    #pragma unroll
    for (int ks = 0; ks < 2; ++ks) {
        #pragma unroll
        for (int nt = 0; nt < 8; ++nt) {
            short8 b;
            #pragma unroll
            for (int j = 0; j < 8; ++j) {
                int k = ks * 32 + q * 8 + j;
                b[j] = (k < KW) ? (short)f2bf(W[(66 + k) * CZ + nt * 16 + n]) : (short)0;
            }
            bfrag[ks][nt] = b;
        }
    }

    const int pblock = blockIdx.x * (CHUNK * NCHUNK);
    const bool fthr = (tid & 3) == 0;   // one flag-thread per pair, spread over all waves
    const int  fpr  = tid >> 2;

    __syncthreads();   // zero-fill visible before chunk-0 staging writes

    // ---- prologue: stage chunk 0 into buffer 0 ----
    {
        const float2* tokv = (const float2*)tok + (size_t)pblock * TOKF2;
        for (int u = tid; u < CHUNK * TOKF2; u += THREADS) {
            float2 d = tokv[u];
            lds_Au[(u / TOKF2) * LDS_AW + (u % TOKF2)] = packbf2(d.x, d.y);
        }
        if (fthr) {
            int p = pblock + fpr;
            int i = p >> 10, j = p & (NSEQ - 1);
            int ai_ = asym[i], aj_ = asym[j], ei_ = eid[i], ej_ = eid[j];
            int si_ = sym[i], sj_ = sym[j], ri_ = res[i], rj_ = res[j];
            bool cs = ai_ == aj_, es = ei_ == ej_;
            int ro = ri_ - rj_ + 32; ro = ro < 0 ? 0 : (ro > 64 ? 64 : ro);
            int dres = cs ? ro : 65;
            int co = si_ - sj_ + 2; co = co < 0 ? 0 : (co > 4 ? 4 : co);
            int dch = (cs || !es) ? 5 : co;
            const unsigned int one = 0x3F80u;   // bf16(1.0)
            unsigned int* ar = lds_Au + fpr * LDS_AW;
            ar[21] = (es ? one : 0u) | ((dch == 0 ? one : 0u) << 16);  // elems 42,43
            ar[22] = (dch == 1 ? one : 0u) | ((dch == 2 ? one : 0u) << 16);
            ar[23] = (dch == 3 ? one : 0u) | ((dch == 4 ? one : 0u) << 16);
            ar[24] = (dch == 5 ? one : 0u);                            // elems 48,49
            lds_flags[fpr] = dres;
        }
    }
    __syncthreads();

    for (int ch = 0; ch < NCHUNK; ++ch) {
        const int par = ch & 1;
        const int p0 = pblock + ch * CHUNK;
        const bool more = (ch + 1 < NCHUNK);

        // ---- prefetch next chunk into registers (HBM latency hides under compute) ----
        float2 pf0, pf1, pf2, pf3, pf4, pf5;
        int ai_, aj_, ei_, ej_, si_, sj_, ri_, rj_;
        if (more) {
            const float2* tokv = (const float2*)tok + (size_t)(p0 + CHUNK) * TOKF2;
            pf0 = tokv[tid];
            pf1 = tokv[tid + 256];
            pf2 = tokv[tid + 512];
            pf3 = tokv[tid + 768];
            pf4 = tokv[tid + 1024];
            if (tid < 64) pf5 = tokv[tid + 1280];
            if (fthr) {
                int p = p0 + CHUNK + fpr;
                int i = p >> 10, j = p & (NSEQ - 1);
                ai_ = asym[i]; aj_ = asym[j]; ei_ = eid[i]; ej_ = eid[j];
                si_ = sym[i]; sj_ = sym[j]; ri_ = res[i]; rj_ = res[j];
            }
        }

        // ---- compute current chunk: 16 pairs x 128 channels per wave ----
        const unsigned int* Abuf = lds_Au + par * (CHUNK * LDS_AW);
        const unsigned short* arow = (const unsigned short*)(Abuf + (wv * 16 + n) * LDS_AW);
        short8 a0 = *(const short8*)(arow + q * 8);
        short8 a1 = *(const short8*)(arow + 32 + q * 8);
        floatx4 acc[8];
        #pragma unroll
        for (int nt = 0; nt < 8; ++nt) {
            floatx4 z = {0.f, 0.f, 0.f, 0.f};
            z = __builtin_amdgcn_mfma_f32_16x16x32_bf16(a0, bfrag[0][nt], z, 0, 0, 0);
            z = __builtin_amdgcn_mfma_f32_16x16x32_bf16(a1, bfrag[1][nt], z, 0, 0, 0);
            acc[nt] = z;
        }

        // ---- epilogue: single gather row (d_res), fp32 add, store ----
        #pragma unroll
        for (int r = 0; r < 4; ++r) {
            int pl = wv * 16 + q * 4 + r;
            int dres = lds_flags[par * CHUNK + pl];
            const float* wres = lds_W + dres * WPAD;
            size_t obase = (size_t)(p0 + pl) * CZ;
            #pragma unroll
            for (int nt = 0; nt < 8; ++nt) {
                int c = nt * 16 + n;
                out[obase + c] = acc[nt][r] + wres[c];
            }
        }

        // ---- write prefetched chunk into the other buffer ----
        if (more) {
            const int parn = par ^ 1;
            unsigned int* Abn = lds_Au + parn * (CHUNK * LDS_AW);
            int u;
            u = tid;        Abn[(u / TOKF2) * LDS_AW + (u % TOKF2)] = packbf2(pf0.x, pf0.y);
            u = tid + 256;  Abn[(u / TOKF2) * LDS_AW + (u % TOKF2)] = packbf2(pf1.x, pf1.y);
            u = tid + 512;  Abn[(u / TOKF2) * LDS_AW + (u % TOKF2)] = packbf2(pf2.x, pf2.y);
            u = tid + 768;  Abn[(u / TOKF2) * LDS_AW + (u % TOKF2)] = packbf2(pf3.x, pf3.y);
            u = tid + 1024; Abn[(u / TOKF2) * LDS_AW + (u % TOKF2)] = packbf2(pf4.x, pf4.y);
            if (tid < 64) {
                u = tid + 1280;
                Abn[(u / TOKF2) * LDS_AW + (u % TOKF2)] = packbf2(pf5.x, pf5.y);
            }
            if (fthr) {
                bool cs = ai_ == aj_, es = ei_ == ej_;
                int ro = ri_ - rj_ + 32; ro = ro < 0 ? 0 : (ro > 64 ? 64 : ro);
                int dres = cs ? ro : 65;
                int co = si_ - sj_ + 2; co = co < 0 ? 0 : (co > 4 ? 4 : co);
                int dch = (cs || !es) ? 5 : co;
                const unsigned int one = 0x3F80u;
                unsigned int* ar = Abn + fpr * LDS_AW;
                ar[21] = (es ? one : 0u) | ((dch == 0 ? one : 0u) << 16);
                ar[22] = (dch == 1 ? one : 0u) | ((dch == 2 ? one : 0u) << 16);
                ar[23] = (dch == 3 ? one : 0u) | ((dch == 4 ? one : 0u) << 16);
                ar[24] = (dch == 5 ? one : 0u);
                lds_flags[parn * CHUNK + fpr] = dres;
            }
            __syncthreads();   // uniform: 'more' depends only on ch
        }
    }
}

extern "C" void kernel_launch(void* const* d_in, const int* in_sizes, int n_in,
                              void* d_out, int out_size, void* d_ws, size_t ws_size,
                              hipStream_t stream) {
    const float* tok = (const float*)d_in[0];   // rel_tok_feat f32
    const float* W   = (const float*)d_in[1];   // W f32
    const int* asym  = (const int*)d_in[2];
    const int* sym   = (const int*)d_in[3];
    const int* eid   = (const int*)d_in[4];
    const int* res   = (const int*)d_in[5];
    float* out = (float*)d_out;

    const int npairs = NSEQ * NSEQ;
    const int grid = npairs / (CHUNK * NCHUNK);  // 2048 blocks
    hipLaunchKernelGGL(relpos_kernel, dim3(grid), dim3(THREADS), 0, stream,
                       tok, W, asym, sym, eid, res, out);
}

// Round 2
// 676.221 us; speedup vs baseline: 1.1474x; 1.0337x over previous
//
#include <hip/hip_runtime.h>

// RelPosEmbedder: out[p,c] = tok[p,:42] @ W[66:108,c] + W[d_res,c] + ent*W[108,c] + W[109+d_chain,c]
// ent + chain terms FOLDED into the MFMA via spare K columns (42..48):
//   A cols 0..41 = tok, col 42 = ent, cols 43..48 = one_hot(d_chain), 49..63 = 0
//   B rows k<49 = W[66+k]  (W rows 66..114 contiguous: tok, ent, chain)
// Epilogue adds W[d_res] from a PACKED-BF16 LDS table (halves LDS -> 3-4 blocks/CU).
// All f32->bf16 via v_cvt_pk_bf16_f32 (1 instr / 2 elems, RNE).
// Double-buffered A tile: register prefetch issued before compute, 1 barrier/chunk.

typedef __attribute__((ext_vector_type(8))) short short8;
typedef __attribute__((ext_vector_type(4))) float floatx4;

#define NSEQ    1024
#define CZ      128
#define CHUNK   64          // pairs per chunk
#define NCHUNK  8           // chunks per block -> 512 pairs/block
#define THREADS 256
#define KW      49          // folded K width: 42 tok + 1 ent + 6 chain
#define TOKF2   21          // float2 elements per pair row (42 f32)
#define LDS_AW  36          // dwords per A row: 32 data (64 bf16) + 4 bank-pad
#define WROW    68          // dwords per lds_Wb row: 64 data (128 bf16) + 4 bank-pad
#define NWROWS  66          // gather rows 0..65 (d_res)

__device__ __forceinline__ unsigned int packbf2(float x, float y) {
    // D.lo = bf16(x), D.hi = bf16(y), RNE (gfx950 v_cvt_pk_bf16_f32)
    unsigned int r;
    asm("v_cvt_pk_bf16_f32 %0, %1, %2" : "=v"(r) : "v"(x), "v"(y));
    return r;
}

__global__ __launch_bounds__(THREADS, 3) void relpos_kernel(
    const float* __restrict__ tok,   // [N*N, 42] f32
    const float* __restrict__ W,     // [115, 128] f32
    const int* __restrict__ asym,
    const int* __restrict__ sym,
    const int* __restrict__ eid,
    const int* __restrict__ res,
    float* __restrict__ out)         // [N*N, 128] f32
{
    __shared__ __align__(16) unsigned int lds_Au[2 * CHUNK * LDS_AW];  // double-buffered A, packed bf16
    __shared__ __align__(16) unsigned int lds_Wb[NWROWS * WROW];       // d_res rows, packed bf16
    __shared__ int lds_flags[2 * CHUNK];                               // d_res per pair, double-buffered

    const int tid  = threadIdx.x;
    const int lane = tid & 63;
    const int wv   = tid >> 6;
    const int n    = lane & 15;   // MFMA col within 16-tile / A row m
    const int q    = lane >> 4;   // quad

    // ---- one-time: stage gather rows 0..65 as packed bf16 ----
    for (int u = tid; u < NWROWS * 64; u += THREADS) {
        int row = u >> 6, d = u & 63;
        float2 w2 = *((const float2*)W + row * 64 + d);
        lds_Wb[row * WROW + d] = packbf2(w2.x, w2.y);
    }
    // ---- one-time: zero both A buffers (K-pad cols 49..63 stay zero forever) ----
    for (int u = tid; u < 2 * CHUNK * LDS_AW; u += THREADS) lds_Au[u] = 0u;

    // ---- one-time: B fragments (W rows 66..114 as bf16, K zero-padded to 64) ----
    short8 bfrag[2][8];
    #pragma unroll
    for (int ks = 0; ks < 2; ++ks) {
        #pragma unroll
        for (int nt = 0; nt < 8; ++nt) {
            unsigned int bu[4];
            #pragma unroll
            for (int j2 = 0; j2 < 4; ++j2) {
                int k0 = ks * 32 + q * 8 + j2 * 2;
                int k1 = k0 + 1;
                float x = (k0 < KW) ? W[(66 + k0) * CZ + nt * 16 + n] : 0.f;
                float y = (k1 < KW) ? W[(66 + k1) * CZ + nt * 16 + n] : 0.f;
                bu[j2] = packbf2(x, y);
            }
            __builtin_memcpy(&bfrag[ks][nt], bu, 16);
        }
    }

    const int pblock = blockIdx.x * (CHUNK * NCHUNK);
    const bool fthr = (tid & 3) == 0;   // one flag-thread per pair, spread over all waves
    const int  fpr  = tid >> 2;

    __syncthreads();   // zero-fill + Wb visible before chunk-0 staging writes

    // ---- prologue: stage chunk 0 into buffer 0 ----
    {
        const float2* tokv = (const float2*)tok + (size_t)pblock * TOKF2;
        for (int u = tid; u < CHUNK * TOKF2; u += THREADS) {
            float2 d = tokv[u];
            lds_Au[(u / TOKF2) * LDS_AW + (u % TOKF2)] = packbf2(d.x, d.y);
        }
        if (fthr) {
            int p = pblock + fpr;
            int i = p >> 10, j = p & (NSEQ - 1);
            bool cs = asym[i] == asym[j];
            bool es = eid[i] == eid[j];
            int ro = res[i] - res[j] + 32; ro = ro < 0 ? 0 : (ro > 64 ? 64 : ro);
            int dres = cs ? ro : 65;
            int co = sym[i] - sym[j] + 2; co = co < 0 ? 0 : (co > 4 ? 4 : co);
            int dch = (cs || !es) ? 5 : co;
            const unsigned int one = 0x3F80u;   // bf16(1.0)
            unsigned int* ar = lds_Au + fpr * LDS_AW;
            ar[21] = (es ? one : 0u) | ((dch == 0 ? one : 0u) << 16);  // elems 42,43
            ar[22] = (dch == 1 ? one : 0u) | ((dch == 2 ? one : 0u) << 16);
            ar[23] = (dch == 3 ? one : 0u) | ((dch == 4 ? one : 0u) << 16);
            ar[24] = (dch == 5 ? one : 0u);                            // elems 48,49
            lds_flags[fpr] = dres;
        }
    }
    __syncthreads();

    for (int ch = 0; ch < NCHUNK; ++ch) {
        const int par = ch & 1;
        const int p0 = pblock + ch * CHUNK;
        const bool more = (ch + 1 < NCHUNK);

        // ---- prefetch next chunk into registers (HBM latency hides under compute) ----
        float2 pf0, pf1, pf2, pf3, pf4, pf5;
        int ai_, aj_, ei_, ej_, si_, sj_, ri_, rj_;
        if (more) {
            const float2* tokv = (const float2*)tok + (size_t)(p0 + CHUNK) * TOKF2;
            pf0 = tokv[tid];
            pf1 = tokv[tid + 256];
            pf2 = tokv[tid + 512];
            pf3 = tokv[tid + 768];
            pf4 = tokv[tid + 1024];
            if (tid < 64) pf5 = tokv[tid + 1280];
            if (fthr) {
                int p = p0 + CHUNK + fpr;
                int i = p >> 10, j = p & (NSEQ - 1);
                ai_ = asym[i]; aj_ = asym[j]; ei_ = eid[i]; ej_ = eid[j];
                si_ = sym[i]; sj_ = sym[j]; ri_ = res[i]; rj_ = res[j];
            }
        }

        // ---- compute current chunk: 16 pairs x 128 channels per wave ----
        const unsigned int* Abuf = lds_Au + par * (CHUNK * LDS_AW);
        const unsigned short* arow = (const unsigned short*)(Abuf + (wv * 16 + n) * LDS_AW);
        short8 a0 = *(const short8*)(arow + q * 8);
        short8 a1 = *(const short8*)(arow + 32 + q * 8);
        floatx4 acc[8];
        #pragma unroll
        for (int nt = 0; nt < 8; ++nt) {
            floatx4 z = {0.f, 0.f, 0.f, 0.f};
            z = __builtin_amdgcn_mfma_f32_16x16x32_bf16(a0, bfrag[0][nt], z, 0, 0, 0);
            z = __builtin_amdgcn_mfma_f32_16x16x32_bf16(a1, bfrag[1][nt], z, 0, 0, 0);
            acc[nt] = z;
        }

        // ---- epilogue: single bf16 gather row (d_res), fp32 add, store ----
        const int hsel = n & 1;
        #pragma unroll
        for (int r = 0; r < 4; ++r) {
            int pl = wv * 16 + q * 4 + r;
            int dres = lds_flags[par * CHUNK + pl];
            const unsigned int* wres = lds_Wb + dres * WROW + (n >> 1);
            float* op = out + (size_t)(p0 + pl) * CZ + n;
            #pragma unroll
            for (int nt = 0; nt < 8; ++nt) {
                unsigned int w = wres[nt * 8];
                unsigned int f = hsel ? (w & 0xffff0000u) : (w << 16);
                op[nt * 16] = acc[nt][r] + __uint_as_float(f);
            }
        }

        // ---- write prefetched chunk into the other buffer ----
        if (more) {
            const int parn = par ^ 1;
            unsigned int* Abn = lds_Au + parn * (CHUNK * LDS_AW);
            int u;
            u = tid;        Abn[(u / TOKF2) * LDS_AW + (u % TOKF2)] = packbf2(pf0.x, pf0.y);
            u = tid + 256;  Abn[(u / TOKF2) * LDS_AW + (u % TOKF2)] = packbf2(pf1.x, pf1.y);
            u = tid + 512;  Abn[(u / TOKF2) * LDS_AW + (u % TOKF2)] = packbf2(pf2.x, pf2.y);
            u = tid + 768;  Abn[(u / TOKF2) * LDS_AW + (u % TOKF2)] = packbf2(pf3.x, pf3.y);
            u = tid + 1024; Abn[(u / TOKF2) * LDS_AW + (u % TOKF2)] = packbf2(pf4.x, pf4.y);
            if (tid < 64) {
                u = tid + 1280;
                Abn[(u / TOKF2) * LDS_AW + (u % TOKF2)] = packbf2(pf5.x, pf5.y);
            }
            if (fthr) {
                bool cs = ai_ == aj_, es = ei_ == ej_;
                int ro = ri_ - rj_ + 32; ro = ro < 0 ? 0 : (ro > 64 ? 64 : ro);
                int dres = cs ? ro : 65;
                int co = si_ - sj_ + 2; co = co < 0 ? 0 : (co > 4 ? 4 : co);
                int dch = (cs || !es) ? 5 : co;
                const unsigned int one = 0x3F80u;
                unsigned int* ar = Abn + fpr * LDS_AW;
                ar[21] = (es ? one : 0u) | ((dch == 0 ? one : 0u) << 16);
                ar[22] = (dch == 1 ? one : 0u) | ((dch == 2 ? one : 0u) << 16);
                ar[23] = (dch == 3 ? one : 0u) | ((dch == 4 ? one : 0u) << 16);
                ar[24] = (dch == 5 ? one : 0u);
                lds_flags[parn * CHUNK + fpr] = dres;
            }
            __syncthreads();   // uniform: 'more' depends only on ch
        }
    }
}

extern "C" void kernel_launch(void* const* d_in, const int* in_sizes, int n_in,
                              void* d_out, int out_size, void* d_ws, size_t ws_size,
                              hipStream_t stream) {
    const float* tok = (const float*)d_in[0];   // rel_tok_feat f32
    const float* W   = (const float*)d_in[1];   // W f32
    const int* asym  = (const int*)d_in[2];
    const int* sym   = (const int*)d_in[3];
    const int* eid   = (const int*)d_in[4];
    const int* res   = (const int*)d_in[5];
    float* out = (float*)d_out;

    const int npairs = NSEQ * NSEQ;
    const int grid = npairs / (CHUNK * NCHUNK);  // 2048 blocks
    hipLaunchKernelGGL(relpos_kernel, dim3(grid), dim3(THREADS), 0, stream,
                       tok, W, asym, sym, eid, res, out);
}